// Round 15
// baseline (5908.437 us; speedup 1.0000x reference)
//
#include <hip/hip_runtime.h>
#include <stdint.h>
#include <math.h>

// NumPy SSE3-baseline numerics: separate mul+add everywhere, no contraction.
#pragma clang fp contract(off)

#define M_TOTAL 104448   // 51*2048
#define N_OUT   904      // 4 + 6*50*3
#define K_DIM   1024

#define BM 64
#define BN 64
#define BK 16            // one numpy SIMD "group" (4 quads x 4 lanes)

typedef float f32x2 __attribute__((ext_vector_type(2)));

// Packed IEEE f32 ops (VOP3P) — two independent muls/adds per lane, identical
// rounding to v_mul_f32/v_add_f32.
__device__ inline f32x2 pk_mul(f32x2 a, f32x2 b) {
    f32x2 d;
    asm("v_pk_mul_f32 %0, %1, %2" : "=v"(d) : "v"(a), "v"(b));
    return d;
}
__device__ inline f32x2 pk_add(f32x2 a, f32x2 b) {
    f32x2 d;
    asm("v_pk_add_f32 %0, %1, %2" : "=v"(d) : "v"(a), "v"(b));
    return d;
}

// ---------------- threefry2x32 (exact JAX/Random123) ----------------
__host__ __device__ inline uint32_t rotl32(uint32_t x, int r) {
    return (x << r) | (x >> (32 - r));
}

__host__ __device__ inline void threefry2x32(uint32_t k0, uint32_t k1,
                                             uint32_t x0, uint32_t x1,
                                             uint32_t& o0, uint32_t& o1) {
    uint32_t ks2 = k0 ^ k1 ^ 0x1BD11BDAu;
    x0 += k0; x1 += k1;
#define R4(a,b,c,d) \
    x0 += x1; x1 = rotl32(x1,(a)); x1 ^= x0; \
    x0 += x1; x1 = rotl32(x1,(b)); x1 ^= x0; \
    x0 += x1; x1 = rotl32(x1,(c)); x1 ^= x0; \
    x0 += x1; x1 = rotl32(x1,(d)); x1 ^= x0;
    R4(13,15,26,6)  x0 += k1;  x1 += ks2 + 1u;
    R4(17,29,16,24) x0 += ks2; x1 += k0  + 2u;
    R4(13,15,26,6)  x0 += k0;  x1 += k1  + 3u;
    R4(17,29,16,24) x0 += k1;  x1 += ks2 + 4u;
    R4(13,15,26,6)  x0 += ks2; x1 += k0  + 5u;
#undef R4
    o0 = x0; o1 = x1;
}

// jax_threefry_partitionable random_bits:
// element j: block = threefry2x32(key, (0, j)); 32-bit out = o0 ^ o1.
__device__ inline uint32_t random_bits_part(uint32_t k0, uint32_t k1, uint32_t idx) {
    uint32_t o0, o1;
    threefry2x32(k0, k1, 0u, idx, o0, o1);
    return o0 ^ o1;
}

__device__ inline float bits_to_unit(uint32_t bits) {
    return __uint_as_float((bits >> 9) | 0x3f800000u) - 1.0f;
}

// Correctly-rounded f32 transcendentals via double evaluation.
__device__ inline float logf_cr(float x) { return (float)log((double)x); }
__device__ inline float expf_cr(float x) { return (float)exp((double)x); }

__device__ inline float gumbel_at(uint32_t k0, uint32_t k1, uint32_t idx) {
    float f = bits_to_unit(random_bits_part(k0, k1, idx));
    float u = fmaxf(f, 1.17549435e-38f);   // uniform(tiny, 1)
    float t = logf_cr(u);
    return -logf_cr(-t);
}

// ErfInv (f32), Giles polynomial — continuous path, bf16-invisible tolerance
__device__ inline float erfinv_xla(float x) {
    float w = -log1pf(-x * x);
    float p;
    if (w < 5.0f) {
        w = w - 2.5f;
        p = 2.81022636e-08f;
        p = 3.43273939e-07f  + p * w;
        p = -3.5233877e-06f  + p * w;
        p = -4.39150654e-06f + p * w;
        p = 0.00021858087f   + p * w;
        p = -0.00125372503f  + p * w;
        p = -0.00417768164f  + p * w;
        p = 0.246640727f     + p * w;
        p = 1.50140941f      + p * w;
    } else {
        w = sqrtf(w) - 3.0f;
        p = -0.000200214257f;
        p = 0.000100950558f  + p * w;
        p = 0.00134934322f   + p * w;
        p = -0.00367342844f  + p * w;
        p = 0.00573950773f   + p * w;
        p = -0.0076224613f   + p * w;
        p = 0.00943887047f   + p * w;
        p = 1.00167406f      + p * w;
        p = 2.83297682f      + p * w;
    }
    return p * x;
}

// ---------------- Kernel A: numpy SSE3 SOP replica, A-in-reg + B-in-LDS ----------------
// Bit-identical arithmetic to the R10/R12/R14 pass kernels:
//   per output, 4 mod-4 chain accumulators; groups of 16 ascending; quads
//   within a group visited in REVERSE (q=3..0); p = a*b then acc = p + acc
//   (separate roundings, no fma); fold (s0+s1)+(s2+s3); + bias.
// Perf structure:
//   - A: global->VGPR per quad (4 rows x dwordx4), double-buffered one quad
//     ahead; 128 packed instrs (256 cyc) cover L1/L2 latency. No A in LDS.
//   - B: LDS, skewed elem = n + 2*(n>>2) (row 100 f32x2): b128 reads 2-way max.
//   - next K-tile's B global load issued before current compute.
__global__ __launch_bounds__(256) void gemm_np_sse_rAq(
    const float* __restrict__ X,      // (rows, 1024) — already offset to chunk
    const float* __restrict__ W,      // (904, 1024)
    const float* __restrict__ bias,   // (904,)
    float* __restrict__ ret,          // (rows, 904)
    int rows)
{
    __shared__ f32x2 Bs2[8][100];   // [kpair][n + 2*(n>>2)]  6400 B

    const int t  = threadIdx.x;
    const int tx = t & 15;     // n dir (4 cols each)
    const int ty = t >> 4;     // m dir (4 rows each)
    const int m0 = blockIdx.y * BM;
    const int n0 = blockIdx.x * BN;

    const int sn  = t >> 2;        // 0..63 staged col index
    const int skq = t & 3;         // 0..3  staged k-quad
    const int bse = sn + 2 * (sn >> 2);   // skewed B store element

    const float* Wrow = W + (size_t)(n0 + sn) * K_DIM + skq * 4;
    const bool   wok  = (n0 + sn) < N_OUT;

    // A row base pointers (4 rows owned by this thread)
    const float* Ar0 = X + (size_t)(m0 + ty * 4 + 0) * K_DIM;
    const float* Ar1 = X + (size_t)(m0 + ty * 4 + 1) * K_DIM;
    const float* Ar2 = X + (size_t)(m0 + ty * 4 + 2) * K_DIM;
    const float* Ar3 = X + (size_t)(m0 + ty * 4 + 3) * K_DIM;

    // acc[half][i][j]: half0 = chains k%4 in {0,1}, half1 = {2,3}
    f32x2 acc[2][4][4];
#pragma unroll
    for (int h = 0; h < 2; h++)
#pragma unroll
        for (int i = 0; i < 4; i++)
#pragma unroll
            for (int j = 0; j < 4; j++) acc[h][i][j] = (f32x2){0.0f, 0.0f};

    float4 A0[4], A1[4];       // quad buffers (4 rows x 16B), static names

#define LOADQ(BUF, KO)                                   \
    do { const int _ko = (KO);                           \
        BUF[0] = *(const float4*)(Ar0 + _ko);            \
        BUF[1] = *(const float4*)(Ar1 + _ko);            \
        BUF[2] = *(const float4*)(Ar2 + _ko);            \
        BUF[3] = *(const float4*)(Ar3 + _ko);            \
    } while (0)

    // COMPUTE_Q: one quad = chains h=0 (lanes .x,.y) and h=1 (.z,.w)
#define COMPUTE_Q(BUF, Q)                                                  \
    do {                                                                   \
        _Pragma("unroll")                                                  \
        for (int h = 0; h < 2; h++) {                                      \
            const int kp = (Q) * 2 + h;                                    \
            float4 bb0 = *(const float4*)&Bs2[kp][tx * 6];                 \
            float4 bb1 = *(const float4*)&Bs2[kp][tx * 6 + 2];             \
            f32x2 b0 = {bb0.x, bb0.y}, b1 = {bb0.z, bb0.w};                \
            f32x2 b2 = {bb1.x, bb1.y}, b3 = {bb1.z, bb1.w};                \
            f32x2 a0 = h ? (f32x2){BUF[0].z, BUF[0].w} : (f32x2){BUF[0].x, BUF[0].y}; \
            f32x2 a1 = h ? (f32x2){BUF[1].z, BUF[1].w} : (f32x2){BUF[1].x, BUF[1].y}; \
            f32x2 a2 = h ? (f32x2){BUF[2].z, BUF[2].w} : (f32x2){BUF[2].x, BUF[2].y}; \
            f32x2 a3 = h ? (f32x2){BUF[3].z, BUF[3].w} : (f32x2){BUF[3].x, BUF[3].y}; \
            acc[h][0][0] = pk_add(pk_mul(a0, b0), acc[h][0][0]);           \
            acc[h][0][1] = pk_add(pk_mul(a0, b1), acc[h][0][1]);           \
            acc[h][0][2] = pk_add(pk_mul(a0, b2), acc[h][0][2]);           \
            acc[h][0][3] = pk_add(pk_mul(a0, b3), acc[h][0][3]);           \
            acc[h][1][0] = pk_add(pk_mul(a1, b0), acc[h][1][0]);           \
            acc[h][1][1] = pk_add(pk_mul(a1, b1), acc[h][1][1]);           \
            acc[h][1][2] = pk_add(pk_mul(a1, b2), acc[h][1][2]);           \
            acc[h][1][3] = pk_add(pk_mul(a1, b3), acc[h][1][3]);           \
            acc[h][2][0] = pk_add(pk_mul(a2, b0), acc[h][2][0]);           \
            acc[h][2][1] = pk_add(pk_mul(a2, b1), acc[h][2][1]);           \
            acc[h][2][2] = pk_add(pk_mul(a2, b2), acc[h][2][2]);           \
            acc[h][2][3] = pk_add(pk_mul(a2, b3), acc[h][2][3]);           \
            acc[h][3][0] = pk_add(pk_mul(a3, b0), acc[h][3][0]);           \
            acc[h][3][1] = pk_add(pk_mul(a3, b1), acc[h][3][1]);           \
            acc[h][3][2] = pk_add(pk_mul(a3, b2), acc[h][3][2]);           \
            acc[h][3][3] = pk_add(pk_mul(a3, b3), acc[h][3][3]);           \
        }                                                                  \
    } while (0)

    // prefetch tile 0: B staging value and A quad q=3
    float4 bv = wok ? *(const float4*)(Wrow) : make_float4(0.f, 0.f, 0.f, 0.f);
    LOADQ(A0, 12);             // tile 0, q=3 (k offset 12)

    for (int k0 = 0; k0 < K_DIM; k0 += BK) {
        __syncthreads();           // previous tile's B reads complete
        Bs2[skq * 2 + 0][bse] = (f32x2){bv.x, bv.y};
        Bs2[skq * 2 + 1][bse] = (f32x2){bv.z, bv.w};
        __syncthreads();

        // issue next tile's B global load now; compute hides latency
        if (k0 + BK < K_DIM)
            bv = wok ? *(const float4*)(Wrow + k0 + BK)
                     : make_float4(0.f, 0.f, 0.f, 0.f);

        // numpy reverse-quad order q = 3,2,1,0; A double-buffered per quad
        COMPUTE_Q(A0, 3); LOADQ(A1, k0 + 8);     // fetch q=2
        COMPUTE_Q(A1, 2); LOADQ(A0, k0 + 4);     // fetch q=1
        COMPUTE_Q(A0, 1); LOADQ(A1, k0 + 0);     // fetch q=0
        COMPUTE_Q(A1, 0);
        if (k0 + BK < K_DIM) LOADQ(A0, k0 + BK + 12);   // next tile q=3
    }
#undef LOADQ
#undef COMPUTE_Q

    // epilogue: hadd tree fold (s0+s1)+(s2+s3), + bias, store
#pragma unroll
    for (int i = 0; i < 4; i++) {
        int m = m0 + ty * 4 + i;
        if (m >= rows) continue;
#pragma unroll
        for (int j = 0; j < 4; j++) {
            int o = n0 + tx * 4 + j;
            if (o >= N_OUT) continue;
            f32x2 s01 = acc[0][i][j];
            f32x2 s23 = acc[1][i][j];
            float res = (s01.x + s01.y) + (s23.x + s23.y);
            ret[(size_t)m * N_OUT + o] = res + bias[o];
        }
    }
}

// ---------------- Kernel B: sampling (one wave per (s,b) row) ----------------
__global__ __launch_bounds__(256) void sample_kernel(
    const float* __restrict__ ret,   // (rows, 904) chunk
    float* __restrict__ out,         // (M_TOTAL, 10)
    int m0_global, int rows,
    uint32_t kc0, uint32_t kc1,
    uint32_t km0, uint32_t km1,
    uint32_t kg0, uint32_t kg1)
{
    const int lane = threadIdx.x & 63;
    const int wid  = threadIdx.x >> 6;
    const int rloc = blockIdx.x * 4 + wid;
    if (rloc >= rows) return;
    const int m = m0_global + rloc;

    const float* r = ret + (size_t)rloc * N_OUT;
    float* o = out + (size_t)m * 10;

    const float LO = __uint_as_float(0xBF7FFFFFu);      // nextafter(-1, 0)
    const float SQRT2 = __uint_as_float(0x3FB504F3u);   // f32(sqrt(2))

    // ---- command: argmax(ret[:4]/1e-4 + gumbel) ----
    {
        float v; int idx = lane;
        if (lane < 4) {
            float g = gumbel_at(kc0, kc1, (uint32_t)(m * 4 + lane));
            v = r[lane] / 0.0001f + g;
        } else {
            v = -INFINITY;
        }
#pragma unroll
        for (int off = 1; off < 64; off <<= 1) {
            float v2 = __shfl_xor(v, off);
            int   i2 = __shfl_xor(idx, off);
            if (v2 > v || (v2 == v && i2 < idx)) { v = v2; idx = i2; }
        }
        if (lane < 4) o[lane] = (lane == idx) ? 1.0f : 0.0f;
    }

    // ---- 6 mixture groups ----
    for (int a = 0; a < 6; a++) {
        const float* base = r + 4 + a * 150;
        float l = (lane < 50) ? base[lane] : -INFINITY;

        float mx = l;
#pragma unroll
        for (int off = 1; off < 64; off <<= 1) mx = fmaxf(mx, __shfl_xor(mx, off));

        float e = (lane < 50) ? expf_cr(l - mx) : 0.0f;

        // numpy pairwise sum, n=50
        float rj = (lane < 8) ? e : 0.0f;
#pragma unroll
        for (int tstep = 1; tstep <= 5; tstep++) {
            float ev = __shfl(e, (lane & 7) + 8 * tstep);
            if (lane < 8) rj = rj + ev;
        }
        float r0 = __shfl(rj, 0), r1 = __shfl(rj, 1), r2 = __shfl(rj, 2), r3 = __shfl(rj, 3);
        float r4 = __shfl(rj, 4), r5 = __shfl(rj, 5), r6 = __shfl(rj, 6), r7 = __shfl(rj, 7);
        float s = ((r0 + r1) + (r2 + r3)) + ((r4 + r5) + (r6 + r7));
        s = s + __shfl(e, 48);
        s = s + __shfl(e, 49);

        float lse = logf_cr(s) + mx;

        float vv; int ii = lane;
        if (lane < 50) {
            float g = gumbel_at(km0, km1, (uint32_t)((m * 6 + a) * 50 + lane));
            vv = (l - lse) / 0.0001f + g;
        } else {
            vv = -INFINITY;
        }
#pragma unroll
        for (int off = 1; off < 64; off <<= 1) {
            float v2 = __shfl_xor(vv, off);
            int   i2 = __shfl_xor(ii, off);
            if (v2 > vv || (v2 == vv && i2 < ii)) { vv = v2; ii = i2; }
        }

        if (lane == 0) {
            float mean = base[50 + ii];
            float lstd = base[100 + ii];
            uint32_t eidx = (uint32_t)(m * 6 + a);
            float f = bits_to_unit(random_bits_part(kg0, kg1, eidx));
            float val = f * 2.0f + LO;        // f*(hi-lo)+lo, (hi-lo) rounds to 2.0f
            val = fmaxf(LO, val);
            float nrm = SQRT2 * erfinv_xla(val);
            float noise = nrm * 0.01f;        // * f32(sqrt(1e-4))
            o[4 + a] = mean + expf_cr(lstd) * noise;
        }
    }
}

// ---------------- host ----------------
extern "C" void kernel_launch(void* const* d_in, const int* in_sizes, int n_in,
                              void* d_out, int out_size, void* d_ws, size_t ws_size,
                              hipStream_t stream) {
    const float* X    = (const float*)d_in[0];  // (51,2048,1024)
    const float* W    = (const float*)d_in[1];  // (904,1024)
    const float* bias = (const float*)d_in[2];  // (904,)
    float* out = (float*)d_out;                 // (51,2048,10)
    float* ws  = (float*)d_ws;

    // key(42) = (0,42); partitionable (fold-like) split into 3:
    // key_i = full cipher block threefry2x32(key, (0, i))
    uint32_t kc0, kc1, km0, km1, kg0, kg1;
    threefry2x32(0u, 42u, 0u, 0u, kc0, kc1);   // k_cmd
    threefry2x32(0u, 42u, 0u, 1u, km0, km1);   // k_mix
    threefry2x32(0u, 42u, 0u, 2u, kg0, kg1);   // k_gauss

    const size_t rowBytes = (size_t)N_OUT * sizeof(float);
    size_t rowsCap = ws_size / rowBytes;
    int chunk = (rowsCap >= (size_t)M_TOTAL) ? M_TOTAL : (int)rowsCap;
    chunk -= chunk % BM;
    if (chunk <= 0) chunk = BM;

    const int gx = (N_OUT + BN - 1) / BN;

    for (int m0 = 0; m0 < M_TOTAL; m0 += chunk) {
        int rows = M_TOTAL - m0;
        if (rows > chunk) rows = chunk;
        dim3 ggrid(gx, rows / BM);
        gemm_np_sse_rAq<<<ggrid, 256, 0, stream>>>(X + (size_t)m0 * K_DIM, W, bias, ws, rows);
        sample_kernel<<<dim3(rows / 4), 256, 0, stream>>>(ws, out, m0, rows,
                                                          kc0, kc1, km0, km1, kg0, kg1);
    }
}

// Round 16
// 4890.137 us; speedup vs baseline: 1.2082x; 1.2082x over previous
//
#include <hip/hip_runtime.h>
#include <stdint.h>
#include <math.h>

// NumPy SSE3-baseline numerics: separate mul+add everywhere, no contraction.
#pragma clang fp contract(off)

#define M_TOTAL 104448   // 51*2048
#define N_OUT   904      // 4 + 6*50*3
#define K_DIM   1024
#define HALF_M  52224    // A/B split (816*64)

#define BM 64
#define BN 64
#define BK 16            // one numpy SIMD "group" (4 quads x 4 lanes)

typedef float f32x2 __attribute__((ext_vector_type(2)));

// One numpy MAC step on two chains: p = a*b (one rounding), acc = p + acc
// (one rounding). Two codegen strategies, bit-identical results:
//   V=0: plain vector ops — LLVM packed-fp32 path, perfect regalloc
//   V=1: inline asm, accumulator tied in-place ("+v") — moves impossible
template<int V>
__device__ inline void mac(f32x2& acc, f32x2 a, f32x2 b) {
    if constexpr (V == 0) {
        f32x2 p = a * b;
        acc = p + acc;
    } else {
        f32x2 p;
        asm("v_pk_mul_f32 %0, %1, %2" : "=v"(p) : "v"(a), "v"(b));
        asm("v_pk_add_f32 %0, %1, %0" : "+v"(acc) : "v"(p));
    }
}

// ---------------- threefry2x32 (exact JAX/Random123) ----------------
__host__ __device__ inline uint32_t rotl32(uint32_t x, int r) {
    return (x << r) | (x >> (32 - r));
}

__host__ __device__ inline void threefry2x32(uint32_t k0, uint32_t k1,
                                             uint32_t x0, uint32_t x1,
                                             uint32_t& o0, uint32_t& o1) {
    uint32_t ks2 = k0 ^ k1 ^ 0x1BD11BDAu;
    x0 += k0; x1 += k1;
#define R4(a,b,c,d) \
    x0 += x1; x1 = rotl32(x1,(a)); x1 ^= x0; \
    x0 += x1; x1 = rotl32(x1,(b)); x1 ^= x0; \
    x0 += x1; x1 = rotl32(x1,(c)); x1 ^= x0; \
    x0 += x1; x1 = rotl32(x1,(d)); x1 ^= x0;
    R4(13,15,26,6)  x0 += k1;  x1 += ks2 + 1u;
    R4(17,29,16,24) x0 += ks2; x1 += k0  + 2u;
    R4(13,15,26,6)  x0 += k0;  x1 += k1  + 3u;
    R4(17,29,16,24) x0 += k1;  x1 += ks2 + 4u;
    R4(13,15,26,6)  x0 += ks2; x1 += k0  + 5u;
#undef R4
    o0 = x0; o1 = x1;
}

// jax_threefry_partitionable random_bits:
// element j: block = threefry2x32(key, (0, j)); 32-bit out = o0 ^ o1.
__device__ inline uint32_t random_bits_part(uint32_t k0, uint32_t k1, uint32_t idx) {
    uint32_t o0, o1;
    threefry2x32(k0, k1, 0u, idx, o0, o1);
    return o0 ^ o1;
}

__device__ inline float bits_to_unit(uint32_t bits) {
    return __uint_as_float((bits >> 9) | 0x3f800000u) - 1.0f;
}

// Correctly-rounded f32 transcendentals via double evaluation.
__device__ inline float logf_cr(float x) { return (float)log((double)x); }
__device__ inline float expf_cr(float x) { return (float)exp((double)x); }

__device__ inline float gumbel_at(uint32_t k0, uint32_t k1, uint32_t idx) {
    float f = bits_to_unit(random_bits_part(k0, k1, idx));
    float u = fmaxf(f, 1.17549435e-38f);   // uniform(tiny, 1)
    float t = logf_cr(u);
    return -logf_cr(-t);
}

// ErfInv (f32), Giles polynomial — continuous path, bf16-invisible tolerance
__device__ inline float erfinv_xla(float x) {
    float w = -log1pf(-x * x);
    float p;
    if (w < 5.0f) {
        w = w - 2.5f;
        p = 2.81022636e-08f;
        p = 3.43273939e-07f  + p * w;
        p = -3.5233877e-06f  + p * w;
        p = -4.39150654e-06f + p * w;
        p = 0.00021858087f   + p * w;
        p = -0.00125372503f  + p * w;
        p = -0.00417768164f  + p * w;
        p = 0.246640727f     + p * w;
        p = 1.50140941f      + p * w;
    } else {
        w = sqrtf(w) - 3.0f;
        p = -0.000200214257f;
        p = 0.000100950558f  + p * w;
        p = 0.00134934322f   + p * w;
        p = -0.00367342844f  + p * w;
        p = 0.00573950773f   + p * w;
        p = -0.0076224613f   + p * w;
        p = 0.00943887047f   + p * w;
        p = 1.00167406f      + p * w;
        p = 2.83297682f      + p * w;
    }
    return p * x;
}

// ---------------- Kernel A: numpy SSE3 SOP replica (R14 structure) ----------------
// Bit-identical arithmetic to the R10/R12/R14 pass kernels:
//   per output, 4 mod-4 chain accumulators; groups of 16 ascending; quads
//   within a group visited in REVERSE (q=3..0); p = a*b then acc = p + acc
//   (separate roundings, no fma); fold (s0+s1)+(s2+s3); + bias.
// LDS: A rows padded to 68 f32x2; B skewed elem = n + 2*(n>>2) (row 100):
// b128 reads <=2-way conflicts. Next tile's globals prefetched pre-compute.
template<int V>
__global__ __launch_bounds__(256) void gemm_np_sse_v(
    const float* __restrict__ X,      // (rows, 1024) — already offset
    const float* __restrict__ W,      // (904, 1024)
    const float* __restrict__ bias,   // (904,)
    float* __restrict__ ret,          // (rows, 904) — already offset
    int rows)
{
    __shared__ f32x2 As2[8][68];    // [kpair][m]            4352 B
    __shared__ f32x2 Bs2[8][100];   // [kpair][n + 2*(n>>2)] 6400 B

    const int t  = threadIdx.x;
    const int tx = t & 15;     // n dir (4 cols each)
    const int ty = t >> 4;     // m dir (4 rows each)
    const int m0 = blockIdx.y * BM;
    const int n0 = blockIdx.x * BN;

    const int sm  = t >> 2;        // 0..63 staged row index
    const int skq = t & 3;         // 0..3  staged k-quad
    const int bse = sm + 2 * (sm >> 2);   // skewed B store element

    const float* Xrow = X + (size_t)(m0 + sm) * K_DIM + skq * 4;
    const float* Wrow = W + (size_t)(n0 + sm) * K_DIM + skq * 4;
    const bool   wok  = (n0 + sm) < N_OUT;

    // acc[half][i][j]: half0 = chains k%4 in {0,1}, half1 = {2,3}
    f32x2 acc[2][4][4];
#pragma unroll
    for (int h = 0; h < 2; h++)
#pragma unroll
        for (int i = 0; i < 4; i++)
#pragma unroll
            for (int j = 0; j < 4; j++) acc[h][i][j] = (f32x2){0.0f, 0.0f};

    // prefetch tile 0
    float4 av = *(const float4*)(Xrow);
    float4 bv = wok ? *(const float4*)(Wrow) : make_float4(0.f, 0.f, 0.f, 0.f);

    for (int k0 = 0; k0 < K_DIM; k0 += BK) {
        __syncthreads();           // previous tile's reads complete
        As2[skq * 2 + 0][sm]  = (f32x2){av.x, av.y};
        As2[skq * 2 + 1][sm]  = (f32x2){av.z, av.w};
        Bs2[skq * 2 + 0][bse] = (f32x2){bv.x, bv.y};
        Bs2[skq * 2 + 1][bse] = (f32x2){bv.z, bv.w};
        __syncthreads();

        // issue next tile's global loads now; compute below hides latency
        if (k0 + BK < K_DIM) {
            av = *(const float4*)(Xrow + k0 + BK);
            bv = wok ? *(const float4*)(Wrow + k0 + BK)
                     : make_float4(0.f, 0.f, 0.f, 0.f);
        }

        // numpy reverse-quad order q=3..0; kp = 2q+h covers chains {2h,2h+1}
#pragma unroll
        for (int q = 3; q >= 0; q--) {
#pragma unroll
            for (int h = 0; h < 2; h++) {
                const int kp = q * 2 + h;
                float4 aa0 = *(const float4*)&As2[kp][ty * 4];      // rows 0,1
                float4 aa1 = *(const float4*)&As2[kp][ty * 4 + 2];  // rows 2,3
                float4 bb0 = *(const float4*)&Bs2[kp][tx * 6];      // cols 0,1
                float4 bb1 = *(const float4*)&Bs2[kp][tx * 6 + 2];  // cols 2,3
                f32x2 a0 = {aa0.x, aa0.y}, a1 = {aa0.z, aa0.w};
                f32x2 a2 = {aa1.x, aa1.y}, a3 = {aa1.z, aa1.w};
                f32x2 b0 = {bb0.x, bb0.y}, b1 = {bb0.z, bb0.w};
                f32x2 b2 = {bb1.x, bb1.y}, b3 = {bb1.z, bb1.w};
                mac<V>(acc[h][0][0], a0, b0); mac<V>(acc[h][0][1], a0, b1);
                mac<V>(acc[h][0][2], a0, b2); mac<V>(acc[h][0][3], a0, b3);
                mac<V>(acc[h][1][0], a1, b0); mac<V>(acc[h][1][1], a1, b1);
                mac<V>(acc[h][1][2], a1, b2); mac<V>(acc[h][1][3], a1, b3);
                mac<V>(acc[h][2][0], a2, b0); mac<V>(acc[h][2][1], a2, b1);
                mac<V>(acc[h][2][2], a2, b2); mac<V>(acc[h][2][3], a2, b3);
                mac<V>(acc[h][3][0], a3, b0); mac<V>(acc[h][3][1], a3, b1);
                mac<V>(acc[h][3][2], a3, b2); mac<V>(acc[h][3][3], a3, b3);
            }
        }
    }

    // epilogue: hadd tree fold (s0+s1)+(s2+s3), + bias, store
#pragma unroll
    for (int i = 0; i < 4; i++) {
        int m = m0 + ty * 4 + i;
        if (m >= rows) continue;
#pragma unroll
        for (int j = 0; j < 4; j++) {
            int o = n0 + tx * 4 + j;
            if (o >= N_OUT) continue;
            f32x2 s01 = acc[0][i][j];
            f32x2 s23 = acc[1][i][j];
            float res = (s01.x + s01.y) + (s23.x + s23.y);
            ret[(size_t)m * N_OUT + o] = res + bias[o];
        }
    }
}

// ---------------- Kernel B: sampling (one wave per (s,b) row) ----------------
__global__ __launch_bounds__(256) void sample_kernel(
    const float* __restrict__ ret,   // (rows, 904) chunk
    float* __restrict__ out,         // (M_TOTAL, 10)
    int m0_global, int rows,
    uint32_t kc0, uint32_t kc1,
    uint32_t km0, uint32_t km1,
    uint32_t kg0, uint32_t kg1)
{
    const int lane = threadIdx.x & 63;
    const int wid  = threadIdx.x >> 6;
    const int rloc = blockIdx.x * 4 + wid;
    if (rloc >= rows) return;
    const int m = m0_global + rloc;

    const float* r = ret + (size_t)rloc * N_OUT;
    float* o = out + (size_t)m * 10;

    const float LO = __uint_as_float(0xBF7FFFFFu);      // nextafter(-1, 0)
    const float SQRT2 = __uint_as_float(0x3FB504F3u);   // f32(sqrt(2))

    // ---- command: argmax(ret[:4]/1e-4 + gumbel) ----
    {
        float v; int idx = lane;
        if (lane < 4) {
            float g = gumbel_at(kc0, kc1, (uint32_t)(m * 4 + lane));
            v = r[lane] / 0.0001f + g;
        } else {
            v = -INFINITY;
        }
#pragma unroll
        for (int off = 1; off < 64; off <<= 1) {
            float v2 = __shfl_xor(v, off);
            int   i2 = __shfl_xor(idx, off);
            if (v2 > v || (v2 == v && i2 < idx)) { v = v2; idx = i2; }
        }
        if (lane < 4) o[lane] = (lane == idx) ? 1.0f : 0.0f;
    }

    // ---- 6 mixture groups ----
    for (int a = 0; a < 6; a++) {
        const float* base = r + 4 + a * 150;
        float l = (lane < 50) ? base[lane] : -INFINITY;

        float mx = l;
#pragma unroll
        for (int off = 1; off < 64; off <<= 1) mx = fmaxf(mx, __shfl_xor(mx, off));

        float e = (lane < 50) ? expf_cr(l - mx) : 0.0f;

        // numpy pairwise sum, n=50
        float rj = (lane < 8) ? e : 0.0f;
#pragma unroll
        for (int tstep = 1; tstep <= 5; tstep++) {
            float ev = __shfl(e, (lane & 7) + 8 * tstep);
            if (lane < 8) rj = rj + ev;
        }
        float r0 = __shfl(rj, 0), r1 = __shfl(rj, 1), r2 = __shfl(rj, 2), r3 = __shfl(rj, 3);
        float r4 = __shfl(rj, 4), r5 = __shfl(rj, 5), r6 = __shfl(rj, 6), r7 = __shfl(rj, 7);
        float s = ((r0 + r1) + (r2 + r3)) + ((r4 + r5) + (r6 + r7));
        s = s + __shfl(e, 48);
        s = s + __shfl(e, 49);

        float lse = logf_cr(s) + mx;

        float vv; int ii = lane;
        if (lane < 50) {
            float g = gumbel_at(km0, km1, (uint32_t)((m * 6 + a) * 50 + lane));
            vv = (l - lse) / 0.0001f + g;
        } else {
            vv = -INFINITY;
        }
#pragma unroll
        for (int off = 1; off < 64; off <<= 1) {
            float v2 = __shfl_xor(vv, off);
            int   i2 = __shfl_xor(ii, off);
            if (v2 > vv || (v2 == vv && i2 < ii)) { vv = v2; ii = i2; }
        }

        if (lane == 0) {
            float mean = base[50 + ii];
            float lstd = base[100 + ii];
            uint32_t eidx = (uint32_t)(m * 6 + a);
            float f = bits_to_unit(random_bits_part(kg0, kg1, eidx));
            float val = f * 2.0f + LO;        // f*(hi-lo)+lo, (hi-lo) rounds to 2.0f
            val = fmaxf(LO, val);
            float nrm = SQRT2 * erfinv_xla(val);
            float noise = nrm * 0.01f;        // * f32(sqrt(1e-4))
            o[4 + a] = mean + expf_cr(lstd) * noise;
        }
    }
}

// ---------------- host ----------------
extern "C" void kernel_launch(void* const* d_in, const int* in_sizes, int n_in,
                              void* d_out, int out_size, void* d_ws, size_t ws_size,
                              hipStream_t stream) {
    const float* X    = (const float*)d_in[0];  // (51,2048,1024)
    const float* W    = (const float*)d_in[1];  // (904,1024)
    const float* bias = (const float*)d_in[2];  // (904,)
    float* out = (float*)d_out;                 // (51,2048,10)
    float* ws  = (float*)d_ws;

    // key(42) = (0,42); partitionable (fold-like) split into 3:
    // key_i = full cipher block threefry2x32(key, (0, i))
    uint32_t kc0, kc1, km0, km1, kg0, kg1;
    threefry2x32(0u, 42u, 0u, 0u, kc0, kc1);   // k_cmd
    threefry2x32(0u, 42u, 0u, 1u, km0, km1);   // k_mix
    threefry2x32(0u, 42u, 0u, 2u, kg0, kg1);   // k_gauss

    const size_t rowBytes = (size_t)N_OUT * sizeof(float);
    size_t rowsCap = ws_size / rowBytes;
    int chunk = (rowsCap >= (size_t)M_TOTAL) ? M_TOTAL : (int)rowsCap;
    chunk -= chunk % BM;
    if (chunk <= 0) chunk = BM;

    const int gx = (N_OUT + BN - 1) / BN;

    for (int m0 = 0; m0 < M_TOTAL; m0 += chunk) {
        int rows = M_TOTAL - m0;
        if (rows > chunk) rows = chunk;
        int bend = m0 + rows;

        // variant 0 (compiler packed ops) on global rows [m0, min(bend, HALF_M))
        int e0 = (bend < HALF_M) ? bend : HALF_M;
        if (e0 > m0) {
            int r0 = e0 - m0;
            gemm_np_sse_v<0><<<dim3(gx, r0 / BM), 256, 0, stream>>>(
                X + (size_t)m0 * K_DIM, W, bias, ws, r0);
        }
        // variant 1 (tied-asm) on global rows [max(m0, HALF_M), bend)
        int s1 = (m0 > HALF_M) ? m0 : HALF_M;
        if (bend > s1) {
            int r1 = bend - s1;
            gemm_np_sse_v<1><<<dim3(gx, r1 / BM), 256, 0, stream>>>(
                X + (size_t)s1 * K_DIM, W, bias,
                ws + (size_t)(s1 - m0) * N_OUT, r1);
        }

        sample_kernel<<<dim3(rows / 4), 256, 0, stream>>>(ws, out, m0, rows,
                                                          kc0, kc1, km0, km1, kg0, kg1);
    }
}